// Round 1
// baseline (665.948 us; speedup 1.0000x reference)
//
#include <hip/hip_runtime.h>
#include <hip/hip_bf16.h>
#include <stdint.h>

// Problem constants
#define BB 4
#define TT 4096
#define CC 1024
#define HH 2048
#define MM (BB*TT)       // 16384 rows
#define NCK 32           // chunks along T
#define CKS 128          // chunk size (NCK*CKS == TT)

using short8 = __attribute__((ext_vector_type(8))) short;
using f32x4  = __attribute__((ext_vector_type(4))) float;

__device__ __forceinline__ unsigned short f2bf(float f) {
    union { float f; uint32_t u; } v; v.f = f;
    uint32_t r = v.u + 0x7fffu + ((v.u >> 16) & 1u);   // RNE
    return (unsigned short)(r >> 16);
}
__device__ __forceinline__ float bf2f(unsigned short s) {
    union { uint32_t u; float f; } v; v.u = ((uint32_t)s) << 16;
    return v.f;
}

// ---------------- prep: x fp32 -> bf16 (no transpose) ----------------
__global__ void conv_x_kernel(const float* __restrict__ x, unsigned short* __restrict__ xb, int n4) {
    int i = blockIdx.x * blockDim.x + threadIdx.x;
    if (i >= n4) return;
    float4 v = ((const float4*)x)[i];
    ushort4 o;
    o.x = f2bf(v.x); o.y = f2bf(v.y); o.z = f2bf(v.z); o.w = f2bf(v.w);
    ((ushort4*)xb)[i] = o;
}

// ---------------- prep: W (R x C fp32, row-major) -> W^T (C x R bf16) ----------------
__global__ void transpose_conv_kernel(const float* __restrict__ in, unsigned short* __restrict__ out,
                                      int R, int C) {
    __shared__ float tile[32][33];
    int c0 = blockIdx.x * 32, r0 = blockIdx.y * 32;
    for (int i = threadIdx.y; i < 32; i += 8)
        tile[i][threadIdx.x] = in[(size_t)(r0 + i) * C + c0 + threadIdx.x];
    __syncthreads();
    for (int i = threadIdx.y; i < 32; i += 8)
        out[(size_t)(c0 + i) * R + r0 + threadIdx.x] = f2bf(tile[threadIdx.x][i]);
}

// ---------------- MFMA GEMM: C = A(MxK) * B(KxN), B given transposed (NxK) ----------------
// MODE 0: bf16 out = silu(acc*scale[col])   (S branch)
// MODE 1: bf16 out = acc*scale[col]         (Hm branch)
// MODE 2: fp32 out = acc                    (final projection)
template<int MODE>
__global__ __launch_bounds__(256) void gemm_kernel(
    const unsigned short* __restrict__ A,   // M x K bf16, row stride lda
    const unsigned short* __restrict__ Bt,  // N x K bf16, row stride ldb
    void* __restrict__ Cout,
    const float* __restrict__ scale,
    int Nsz, int Ksz, int lda, int ldb, int ldo)
{
    __shared__ __align__(16) unsigned short As[128 * 32];
    __shared__ __align__(16) unsigned short Bs[128 * 32];

    const int nblk = Nsz >> 7;
    const int mt = blockIdx.x / nblk;
    const int nt = blockIdx.x % nblk;
    const int m0 = mt << 7, n0 = nt << 7;

    const int tid  = threadIdx.x;
    const int lane = tid & 63;
    const int wave = tid >> 6;
    const int l15  = lane & 15;
    const int quad = lane >> 4;
    const int wm = (wave >> 1) * 64;
    const int wn = (wave & 1) * 64;

    f32x4 acc[4][4];
#pragma unroll
    for (int i = 0; i < 4; i++)
#pragma unroll
        for (int j = 0; j < 4; j++) acc[i][j] = {0.f, 0.f, 0.f, 0.f};

    for (int k0 = 0; k0 < Ksz; k0 += 32) {
        // stage 128x32 bf16 tiles of A and Bt via async global->LDS (16B/lane)
#pragma unroll
        for (int it = 0; it < 2; it++) {
            int c  = it * 256 + tid;       // 16B chunk id, 0..511
            int r  = c >> 2;               // tile row 0..127
            int kq = (c & 3) * 8;          // k offset within 32
            const unsigned short* ga = A  + (size_t)(m0 + r) * lda + k0 + kq;
            const unsigned short* gb = Bt + (size_t)(n0 + r) * ldb + k0 + kq;
            __builtin_amdgcn_global_load_lds(
                (const __attribute__((address_space(1))) void*)ga,
                (__attribute__((address_space(3))) void*)&As[c * 8], 16, 0, 0);
            __builtin_amdgcn_global_load_lds(
                (const __attribute__((address_space(1))) void*)gb,
                (__attribute__((address_space(3))) void*)&Bs[c * 8], 16, 0, 0);
        }
        __syncthreads();

        short8 af[4], bf[4];
#pragma unroll
        for (int i = 0; i < 4; i++)
            af[i] = *(const short8*)&As[(wm + i * 16 + l15) * 32 + quad * 8];
#pragma unroll
        for (int j = 0; j < 4; j++)
            bf[j] = *(const short8*)&Bs[(wn + j * 16 + l15) * 32 + quad * 8];
#pragma unroll
        for (int i = 0; i < 4; i++)
#pragma unroll
            for (int j = 0; j < 4; j++)
                acc[i][j] = __builtin_amdgcn_mfma_f32_16x16x32_bf16(af[i], bf[j], acc[i][j], 0, 0, 0);
        __syncthreads();
    }

    // epilogue: C/D layout col=lane&15, row=quad*4+reg
#pragma unroll
    for (int i = 0; i < 4; i++) {
#pragma unroll
        for (int j = 0; j < 4; j++) {
            int col = n0 + wn + j * 16 + l15;
#pragma unroll
            for (int r = 0; r < 4; r++) {
                int row = m0 + wm + i * 16 + quad * 4 + r;
                float v = acc[i][j][r];
                if constexpr (MODE == 0) {
                    v *= scale[col];
                    v = v / (1.f + __expf(-v));
                    ((unsigned short*)Cout)[(size_t)row * ldo + col] = f2bf(v);
                } else if constexpr (MODE == 1) {
                    v *= scale[col];
                    ((unsigned short*)Cout)[(size_t)row * ldo + col] = f2bf(v);
                } else {
                    ((float*)Cout)[(size_t)row * ldo + col] = v;
                }
            }
        }
    }
}

// ---------------- scan phase 1: per-chunk column sums of poly = h1*(1+h2) ----------------
__global__ void chunk_sum_kernel(const unsigned short* __restrict__ h, float* __restrict__ part) {
    int hb = blockIdx.x & 7;               // 8 tiles of 256 h-cols
    int ck = (blockIdx.x >> 3) & (NCK - 1);
    int b  = blockIdx.x >> 8;              // / (8*NCK)
    int hcol = hb * 256 + threadIdx.x;
    size_t base = ((size_t)b * TT + (size_t)ck * CKS) * 4096 + hcol;
    float sum = 0.f;
    for (int t = 0; t < CKS; t++) {
        float a  = bf2f(h[base + (size_t)t * 4096]);
        float b2 = bf2f(h[base + (size_t)t * 4096 + 2048]);
        sum += a * (1.f + b2);
    }
    part[((size_t)b * NCK + ck) * 2048 + hcol] = sum;
}

// ---------------- scan phase 2: exclusive scan over chunks (in place) ----------------
__global__ void chunk_scan_kernel(float* __restrict__ part) {
    int idx = blockIdx.x * blockDim.x + threadIdx.x;   // 8192 = B*H columns
    int b = idx >> 11, hcol = idx & 2047;
    float run = 0.f;
    for (int ck = 0; ck < NCK; ck++) {
        size_t off = ((size_t)b * NCK + ck) * 2048 + hcol;
        float v = part[off];
        part[off] = run;
        run += v;
    }
}

// ---------------- scan phase 3: replay cumsum, M = s * (cumsum/t), in place over h1 ----------------
__global__ void finalize_kernel(unsigned short* __restrict__ h, const unsigned short* __restrict__ s,
                                const float* __restrict__ part) {
    int hb = blockIdx.x & 7;
    int ck = (blockIdx.x >> 3) & (NCK - 1);
    int b  = blockIdx.x >> 8;
    int hcol = hb * 256 + threadIdx.x;
    float run = part[((size_t)b * NCK + ck) * 2048 + hcol];
    for (int t = 0; t < CKS; t++) {
        int tg = ck * CKS + t;
        size_t row = (size_t)b * TT + tg;
        size_t hoff = row * 4096 + hcol;
        float a  = bf2f(h[hoff]);
        float b2 = bf2f(h[hoff + 2048]);
        run += a * (1.f + b2);
        float agg = run / (float)(tg + 1);
        float sv = bf2f(s[row * 2048 + hcol]);
        h[hoff] = f2bf(sv * agg);
    }
}

extern "C" void kernel_launch(void* const* d_in, const int* in_sizes, int n_in,
                              void* d_out, int out_size, void* d_ws, size_t ws_size,
                              hipStream_t stream) {
    const float* x     = (const float*)d_in[0];
    const float* W_sel = (const float*)d_in[1];
    const float* W_agg = (const float*)d_in[2];
    const float* W_out = (const float*)d_in[3];
    const float* sqk_q = (const float*)d_in[4];
    const float* sqk_k = (const float*)d_in[5];
    float* out = (float*)d_out;

    char* ws = (char*)d_ws;
    unsigned short* xb    = (unsigned short*)(ws);                       // 16384x1024 bf16  (32 MB)
    unsigned short* wselT = (unsigned short*)(ws + 33554432ull);         // 2048x1024 bf16   (4 MB)
    unsigned short* waggT = (unsigned short*)(ws + 37748736ull);         // 4096x1024 bf16   (8 MB)
    unsigned short* woutT = (unsigned short*)(ws + 46137344ull);         // 1024x2048 bf16   (4 MB)
    unsigned short* s_b   = (unsigned short*)(ws + 50331648ull);         // 16384x2048 bf16  (64 MB)
    unsigned short* h_b   = (unsigned short*)(ws + 117440512ull);        // 16384x4096 bf16  (128 MB)
    float*          part  = (float*)(ws + 251658240ull);                 // 4x32x2048 fp32   (1 MB)

    // prep
    conv_x_kernel<<<(MM * CC / 4 + 255) / 256, 256, 0, stream>>>(x, xb, MM * CC / 4);
    dim3 tb(32, 8);
    transpose_conv_kernel<<<dim3(HH / 32, CC / 32), tb, 0, stream>>>(W_sel, wselT, CC, HH);
    transpose_conv_kernel<<<dim3(2 * HH / 32, CC / 32), tb, 0, stream>>>(W_agg, waggT, CC, 2 * HH);
    transpose_conv_kernel<<<dim3(CC / 32, HH / 32), tb, 0, stream>>>(W_out, woutT, HH, CC);

    // S = silu(x @ W_sel * sqk_q)           (16384x2048, bf16)
    gemm_kernel<0><<<(MM / 128) * (HH / 128), 256, 0, stream>>>(
        xb, wselT, s_b, sqk_q, HH, CC, CC, CC, HH);
    // Hm = x @ W_agg * sqk_k                (16384x4096, bf16)
    gemm_kernel<1><<<(MM / 128) * (2 * HH / 128), 256, 0, stream>>>(
        xb, waggT, h_b, sqk_k, 2 * HH, CC, CC, CC, 2 * HH);

    // causal running-mean scan + gate -> M, in place over h1 columns of h_b
    chunk_sum_kernel<<<BB * NCK * (HH / 256), 256, 0, stream>>>(h_b, part);
    chunk_scan_kernel<<<(BB * HH) / 256, 256, 0, stream>>>(part);
    finalize_kernel<<<BB * NCK * (HH / 256), 256, 0, stream>>>(h_b, s_b, part);

    // out = M @ W_out                       (16384x1024, fp32)
    gemm_kernel<2><<<(MM / 128) * (CC / 128), 256, 0, stream>>>(
        h_b, woutT, out, nullptr, CC, HH, 2 * HH, HH, CC);
}

// Round 2
// 541.455 us; speedup vs baseline: 1.2299x; 1.2299x over previous
//
#include <hip/hip_runtime.h>
#include <hip/hip_bf16.h>
#include <stdint.h>

#define BB 4
#define TT 4096
#define CC 1024
#define HH 2048
#define MM (BB*TT)       // 16384 rows
#define NCK 32           // chunks along T
#define CKS 128          // chunk size

using short8 = __attribute__((ext_vector_type(8))) short;
using f32x4  = __attribute__((ext_vector_type(4))) float;

__device__ __forceinline__ unsigned short f2bf(float f) {
    union { float f; uint32_t u; } v; v.f = f;
    uint32_t r = v.u + 0x7fffu + ((v.u >> 16) & 1u);   // RNE
    return (unsigned short)(r >> 16);
}
__device__ __forceinline__ float bf2f(unsigned short s) {
    union { uint32_t u; float f; } v; v.u = ((uint32_t)s) << 16;
    return v.f;
}
__device__ __forceinline__ float bf_lo(uint32_t u) {
    union { uint32_t u; float f; } v; v.u = u << 16; return v.f;
}
__device__ __forceinline__ float bf_hi(uint32_t u) {
    union { uint32_t u; float f; } v; v.u = u & 0xFFFF0000u; return v.f;
}
__device__ __forceinline__ uint32_t pack2bf(float lo, float hi) {
    return ((uint32_t)f2bf(lo)) | (((uint32_t)f2bf(hi)) << 16);
}

// ---------------- prep: x fp32 -> bf16 ----------------
__global__ void conv_x_kernel(const float* __restrict__ x, unsigned short* __restrict__ xb, int n4) {
    int i = blockIdx.x * blockDim.x + threadIdx.x;
    if (i >= n4) return;
    float4 v = ((const float4*)x)[i];
    ushort4 o;
    o.x = f2bf(v.x); o.y = f2bf(v.y); o.z = f2bf(v.z); o.w = f2bf(v.w);
    ((ushort4*)xb)[i] = o;
}

// ---------------- prep: out[n][k] = in[k][n] * scale[n]  (in: R x Cin fp32) ----------------
__global__ void trans_direct_kernel(const float* __restrict__ in, unsigned short* __restrict__ out,
                                    const float* __restrict__ scale, int R, int Cin) {
    __shared__ float tile[32][33];
    int c0 = blockIdx.x * 32, k0 = blockIdx.y * 32;
    int tx = threadIdx.x;
    for (int i = threadIdx.y; i < 32; i += 8) {
        float s = scale ? scale[c0 + tx] : 1.f;
        tile[i][tx] = in[(size_t)(k0 + i) * Cin + c0 + tx] * s;
    }
    __syncthreads();
    for (int i = threadIdx.y; i < 32; i += 8)
        out[(size_t)(c0 + i) * R + k0 + tx] = f2bf(tile[tx][i]);
}

// ---------------- prep: pair-permuted W_agg^T with scale ----------------
// out row q (0..4095): g=q>>5, w=q&31; src col = (w<16) ? g*16+w : 2048+g*16+(w-16)
__global__ void trans_pair_kernel(const float* __restrict__ in, unsigned short* __restrict__ out,
                                  const float* __restrict__ scale) {
    __shared__ float tile[32][33];
    int q0 = blockIdx.x * 32, k0 = blockIdx.y * 32;
    int g = q0 >> 5;
    int tx = threadIdx.x;
    int c = (tx < 16) ? (g * 16 + tx) : (2048 + g * 16 + tx - 16);
    float s = scale[c];
    for (int i = threadIdx.y; i < 32; i += 8)
        tile[i][tx] = in[(size_t)(k0 + i) * 4096 + c] * s;
    __syncthreads();
    for (int i = threadIdx.y; i < 32; i += 8)
        out[(size_t)(q0 + i) * 1024 + k0 + tx] = f2bf(tile[tx][i]);
}

// ---------------- fused GEMM: [S | poly] = x @ [W_sel' | W_aggPair'] ----------------
// N = 6144 (nt<16: S silu path; nt>=16: poly path), K = 1024, tiles 128x128
__global__ __launch_bounds__(256) void gemm_fused_kernel(
    const unsigned short* __restrict__ A,    // 16384 x 1024 bf16
    const unsigned short* __restrict__ Bt,   // 6144 x 1024 bf16
    unsigned short* __restrict__ Sout,       // 16384 x 2048 bf16
    unsigned short* __restrict__ Pout)       // 16384 x 2048 bf16 (poly)
{
    __shared__ __align__(16) unsigned short As[128 * 32];
    __shared__ __align__(16) unsigned short Bs[128 * 32];

    const int mt = blockIdx.x / 48;
    const int nt = blockIdx.x % 48;
    const int m0 = mt << 7, n0 = nt << 7;

    const int tid  = threadIdx.x;
    const int lane = tid & 63;
    const int wave = tid >> 6;
    const int l15  = lane & 15;
    const int quad = lane >> 4;
    const int wm = (wave >> 1) * 64;
    const int wn = (wave & 1) * 64;

    f32x4 acc[4][4];
#pragma unroll
    for (int i = 0; i < 4; i++)
#pragma unroll
        for (int j = 0; j < 4; j++) acc[i][j] = {0.f, 0.f, 0.f, 0.f};

    for (int k0 = 0; k0 < 1024; k0 += 32) {
#pragma unroll
        for (int it = 0; it < 2; it++) {
            int c  = it * 256 + tid;
            int r  = c >> 2;
            int kq = (c & 3) * 8;
            const unsigned short* ga = A  + (size_t)(m0 + r) * 1024 + k0 + kq;
            const unsigned short* gb = Bt + (size_t)(n0 + r) * 1024 + k0 + kq;
            __builtin_amdgcn_global_load_lds(
                (const __attribute__((address_space(1))) void*)ga,
                (__attribute__((address_space(3))) void*)&As[c * 8], 16, 0, 0);
            __builtin_amdgcn_global_load_lds(
                (const __attribute__((address_space(1))) void*)gb,
                (__attribute__((address_space(3))) void*)&Bs[c * 8], 16, 0, 0);
        }
        __syncthreads();

        short8 af[4], bf[4];
#pragma unroll
        for (int i = 0; i < 4; i++)
            af[i] = *(const short8*)&As[(wm + i * 16 + l15) * 32 + quad * 8];
#pragma unroll
        for (int j = 0; j < 4; j++)
            bf[j] = *(const short8*)&Bs[(wn + j * 16 + l15) * 32 + quad * 8];
#pragma unroll
        for (int i = 0; i < 4; i++)
#pragma unroll
            for (int j = 0; j < 4; j++)
                acc[i][j] = __builtin_amdgcn_mfma_f32_16x16x32_bf16(af[i], bf[j], acc[i][j], 0, 0, 0);
        __syncthreads();
    }

    if (nt < 16) {
        // S = silu(acc) -> bf16
#pragma unroll
        for (int i = 0; i < 4; i++)
#pragma unroll
            for (int j = 0; j < 4; j++) {
                int col = n0 + wn + j * 16 + l15;
#pragma unroll
                for (int r = 0; r < 4; r++) {
                    int row = m0 + wm + i * 16 + quad * 4 + r;
                    float v = acc[i][j][r];
                    v = v / (1.f + __expf(-v));
                    Sout[(size_t)row * 2048 + col] = f2bf(v);
                }
            }
    } else {
        // poly = h1*(1+h2); fragment j even = h1, j odd = h2, same poly column
        int pbase = ((n0 - 2048 + wn) >> 1);
#pragma unroll
        for (int i = 0; i < 4; i++)
#pragma unroll
            for (int j = 0; j < 4; j += 2) {
                int pcol = pbase + (j >> 1) * 16 + l15;
#pragma unroll
                for (int r = 0; r < 4; r++) {
                    int row = m0 + wm + i * 16 + quad * 4 + r;
                    float a1 = acc[i][j][r];
                    float a2 = acc[i][j + 1][r];
                    Pout[(size_t)row * 2048 + pcol] = f2bf(a1 * (1.f + a2));
                }
            }
    }
}

// ---------------- final GEMM: out = M @ W_out  (16384x2048x1024, fp32 out) ----------------
__global__ __launch_bounds__(256) void gemm_out_kernel(
    const unsigned short* __restrict__ A,    // 16384 x 2048 bf16 (M)
    const unsigned short* __restrict__ Bt,   // 1024 x 2048 bf16
    float* __restrict__ Cout)
{
    __shared__ __align__(16) unsigned short As[128 * 32];
    __shared__ __align__(16) unsigned short Bs[128 * 32];

    const int mt = blockIdx.x >> 3;
    const int nt = blockIdx.x & 7;
    const int m0 = mt << 7, n0 = nt << 7;

    const int tid  = threadIdx.x;
    const int lane = tid & 63;
    const int wave = tid >> 6;
    const int l15  = lane & 15;
    const int quad = lane >> 4;
    const int wm = (wave >> 1) * 64;
    const int wn = (wave & 1) * 64;

    f32x4 acc[4][4];
#pragma unroll
    for (int i = 0; i < 4; i++)
#pragma unroll
        for (int j = 0; j < 4; j++) acc[i][j] = {0.f, 0.f, 0.f, 0.f};

    for (int k0 = 0; k0 < 2048; k0 += 32) {
#pragma unroll
        for (int it = 0; it < 2; it++) {
            int c  = it * 256 + tid;
            int r  = c >> 2;
            int kq = (c & 3) * 8;
            const unsigned short* ga = A  + (size_t)(m0 + r) * 2048 + k0 + kq;
            const unsigned short* gb = Bt + (size_t)(n0 + r) * 2048 + k0 + kq;
            __builtin_amdgcn_global_load_lds(
                (const __attribute__((address_space(1))) void*)ga,
                (__attribute__((address_space(3))) void*)&As[c * 8], 16, 0, 0);
            __builtin_amdgcn_global_load_lds(
                (const __attribute__((address_space(1))) void*)gb,
                (__attribute__((address_space(3))) void*)&Bs[c * 8], 16, 0, 0);
        }
        __syncthreads();

        short8 af[4], bf[4];
#pragma unroll
        for (int i = 0; i < 4; i++)
            af[i] = *(const short8*)&As[(wm + i * 16 + l15) * 32 + quad * 8];
#pragma unroll
        for (int j = 0; j < 4; j++)
            bf[j] = *(const short8*)&Bs[(wn + j * 16 + l15) * 32 + quad * 8];
#pragma unroll
        for (int i = 0; i < 4; i++)
#pragma unroll
            for (int j = 0; j < 4; j++)
                acc[i][j] = __builtin_amdgcn_mfma_f32_16x16x32_bf16(af[i], bf[j], acc[i][j], 0, 0, 0);
        __syncthreads();
    }

#pragma unroll
    for (int i = 0; i < 4; i++)
#pragma unroll
        for (int j = 0; j < 4; j++) {
            int col = n0 + wn + j * 16 + l15;
#pragma unroll
            for (int r = 0; r < 4; r++) {
                int row = m0 + wm + i * 16 + quad * 4 + r;
                Cout[(size_t)row * 1024 + col] = acc[i][j][r];
            }
        }
}

// ---------------- scan phase 1: per-chunk column sums of poly (2 cols/thread) ----------------
__global__ void chunk_sum_kernel(const unsigned short* __restrict__ poly, float* __restrict__ part) {
    int seg = blockIdx.x & 3;
    int ck  = (blockIdx.x >> 2) & (NCK - 1);
    int b   = blockIdx.x >> 7;
    int cp  = seg * 256 + threadIdx.x;          // column pair 0..1023
    size_t base = ((size_t)b * TT + (size_t)ck * CKS) * 2048 + cp * 2;
    float s0 = 0.f, s1 = 0.f;
    for (int t = 0; t < CKS; t++) {
        uint32_t v = *(const uint32_t*)&poly[base + (size_t)t * 2048];
        s0 += bf_lo(v);
        s1 += bf_hi(v);
    }
    size_t po = ((size_t)b * NCK + ck) * 2048 + cp * 2;
    part[po] = s0;
    part[po + 1] = s1;
}

// ---------------- scan phase 2: exclusive scan over chunks ----------------
__global__ void chunk_scan_kernel(float* __restrict__ part) {
    int idx = blockIdx.x * blockDim.x + threadIdx.x;   // 8192 columns
    int b = idx >> 11, col = idx & 2047;
    float run = 0.f;
    for (int ck = 0; ck < NCK; ck++) {
        size_t off = ((size_t)b * NCK + ck) * 2048 + col;
        float v = part[off];
        part[off] = run;
        run += v;
    }
}

// ---------------- scan phase 3: M = s * (cumsum/t), in place over poly ----------------
__global__ void finalize_kernel(unsigned short* __restrict__ poly, const unsigned short* __restrict__ s,
                                const float* __restrict__ part) {
    int seg = blockIdx.x & 3;
    int ck  = (blockIdx.x >> 2) & (NCK - 1);
    int b   = blockIdx.x >> 7;
    int cp  = seg * 256 + threadIdx.x;
    size_t po = ((size_t)b * NCK + ck) * 2048 + cp * 2;
    float run0 = part[po], run1 = part[po + 1];
    size_t base = ((size_t)b * TT + (size_t)ck * CKS) * 2048 + cp * 2;
    for (int t = 0; t < CKS; t++) {
        int tg = ck * CKS + t;
        size_t off = base + (size_t)t * 2048;
        uint32_t pv = *(const uint32_t*)&poly[off];
        run0 += bf_lo(pv);
        run1 += bf_hi(pv);
        float inv = 1.f / (float)(tg + 1);
        uint32_t sv = *(const uint32_t*)&s[off];
        float m0 = bf_lo(sv) * run0 * inv;
        float m1 = bf_hi(sv) * run1 * inv;
        *(uint32_t*)&poly[off] = pack2bf(m0, m1);
    }
}

extern "C" void kernel_launch(void* const* d_in, const int* in_sizes, int n_in,
                              void* d_out, int out_size, void* d_ws, size_t ws_size,
                              hipStream_t stream) {
    const float* x     = (const float*)d_in[0];
    const float* W_sel = (const float*)d_in[1];
    const float* W_agg = (const float*)d_in[2];
    const float* W_out = (const float*)d_in[3];
    const float* sqk_q = (const float*)d_in[4];
    const float* sqk_k = (const float*)d_in[5];
    float* out = (float*)d_out;

    char* ws = (char*)d_ws;
    unsigned short* xb    = (unsigned short*)(ws);                   // 32 MB
    unsigned short* wallT = (unsigned short*)(ws + 33554432ull);     // 6144x1024 bf16 (12 MB)
    unsigned short* woutT = (unsigned short*)(ws + 46137344ull);     // 1024x2048 bf16 (4 MB)
    unsigned short* s_b   = (unsigned short*)(ws + 50331648ull);     // 16384x2048 bf16 (64 MB)
    unsigned short* poly  = (unsigned short*)(ws + 117440512ull);    // 16384x2048 bf16 (64 MB)
    float*          part  = (float*)(ws + 184549376ull);             // 4x32x2048 fp32 (1 MB)

    dim3 tb(32, 8);
    conv_x_kernel<<<(MM * CC / 4 + 255) / 256, 256, 0, stream>>>(x, xb, MM * CC / 4);
    // wallT rows 0..2047: W_sel^T * sqk_q
    trans_direct_kernel<<<dim3(HH / 32, CC / 32), tb, 0, stream>>>(W_sel, wallT, sqk_q, CC, HH);
    // wallT rows 2048..6143: pair-permuted W_agg^T * sqk_k
    trans_pair_kernel<<<dim3(4096 / 32, CC / 32), tb, 0, stream>>>(W_agg, wallT + 2048ull * 1024, sqk_k);
    // woutT: W_out^T
    trans_direct_kernel<<<dim3(CC / 32, HH / 32), tb, 0, stream>>>(W_out, woutT, nullptr, HH, CC);

    // fused: S (silu) + poly, one dispatch
    gemm_fused_kernel<<<(MM / 128) * 48, 256, 0, stream>>>(xb, wallT, s_b, poly);

    // causal running-mean scan + gate -> M (in place over poly)
    chunk_sum_kernel<<<BB * NCK * 4, 256, 0, stream>>>(poly, part);
    chunk_scan_kernel<<<(BB * HH) / 256, 256, 0, stream>>>(part);
    finalize_kernel<<<BB * NCK * 4, 256, 0, stream>>>(poly, s_b, part);

    // out = M @ W_out
    gemm_out_kernel<<<(MM / 128) * (CC / 128), 256, 0, stream>>>(poly, woutT, out);
}

// Round 3
// 525.682 us; speedup vs baseline: 1.2668x; 1.0300x over previous
//
#include <hip/hip_runtime.h>
#include <hip/hip_bf16.h>
#include <stdint.h>

#define BB 4
#define TT 4096
#define CC 1024
#define HH 2048
#define MM (BB*TT)       // 16384 rows
#define NCK 32           // chunks along T
#define CKS 128          // chunk size

using short8 = __attribute__((ext_vector_type(8))) short;
using f32x4  = __attribute__((ext_vector_type(4))) float;

__device__ __forceinline__ unsigned short f2bf(float f) {
    union { float f; uint32_t u; } v; v.f = f;
    uint32_t r = v.u + 0x7fffu + ((v.u >> 16) & 1u);   // RNE
    return (unsigned short)(r >> 16);
}
__device__ __forceinline__ float bf_lo(uint32_t u) {
    union { uint32_t u; float f; } v; v.u = u << 16; return v.f;
}
__device__ __forceinline__ float bf_hi(uint32_t u) {
    union { uint32_t u; float f; } v; v.u = u & 0xFFFF0000u; return v.f;
}
__device__ __forceinline__ uint32_t pack2bf(float lo, float hi) {
    return ((uint32_t)f2bf(lo)) | (((uint32_t)f2bf(hi)) << 16);
}

// ---------------- prep: x fp32 -> bf16 ----------------
__global__ void conv_x_kernel(const float* __restrict__ x, unsigned short* __restrict__ xb, int n4) {
    int i = blockIdx.x * blockDim.x + threadIdx.x;
    if (i >= n4) return;
    float4 v = ((const float4*)x)[i];
    ushort4 o;
    o.x = f2bf(v.x); o.y = f2bf(v.y); o.z = f2bf(v.z); o.w = f2bf(v.w);
    ((ushort4*)xb)[i] = o;
}

// ---------------- prep: out[n][k] = in[k][n] * scale[n]  (in: R x Cin fp32) ----------------
__global__ void trans_direct_kernel(const float* __restrict__ in, unsigned short* __restrict__ out,
                                    const float* __restrict__ scale, int R, int Cin) {
    __shared__ float tile[32][33];
    int c0 = blockIdx.x * 32, k0 = blockIdx.y * 32;
    int tx = threadIdx.x;
    for (int i = threadIdx.y; i < 32; i += 8) {
        float s = scale ? scale[c0 + tx] : 1.f;
        tile[i][tx] = in[(size_t)(k0 + i) * Cin + c0 + tx] * s;
    }
    __syncthreads();
    for (int i = threadIdx.y; i < 32; i += 8)
        out[(size_t)(c0 + i) * R + k0 + tx] = f2bf(tile[tx][i]);
}

// ---------------- prep: pair-permuted W_agg^T with scale ----------------
__global__ void trans_pair_kernel(const float* __restrict__ in, unsigned short* __restrict__ out,
                                  const float* __restrict__ scale) {
    __shared__ float tile[32][33];
    int q0 = blockIdx.x * 32, k0 = blockIdx.y * 32;
    int g = q0 >> 5;
    int tx = threadIdx.x;
    int c = (tx < 16) ? (g * 16 + tx) : (2048 + g * 16 + tx - 16);
    float s = scale[c];
    for (int i = threadIdx.y; i < 32; i += 8)
        tile[i][tx] = in[(size_t)(k0 + i) * 4096 + c] * s;
    __syncthreads();
    for (int i = threadIdx.y; i < 32; i += 8)
        out[(size_t)(q0 + i) * 1024 + k0 + tx] = f2bf(tile[tx][i]);
}

// ---------------- fused GEMM: [S | poly] = x @ [W_sel' | W_aggPair'] ----------------
// BK=64 with XOR-8 LDS swizzle; also emits per-chunk poly column sums into part.
__global__ __launch_bounds__(256) void gemm_fused_kernel(
    const unsigned short* __restrict__ A,    // 16384 x 1024 bf16
    const unsigned short* __restrict__ Bt,   // 6144 x 1024 bf16
    unsigned short* __restrict__ Sout,       // 16384 x 2048 bf16
    unsigned short* __restrict__ Pout,       // 16384 x 2048 bf16 (poly)
    float* __restrict__ part)                // B x NCK x 2048 chunk sums
{
    __shared__ __align__(16) unsigned short As[128 * 64];
    __shared__ __align__(16) unsigned short Bs[128 * 64];
    __shared__ float psum[64];

    const int mt = blockIdx.x / 48;
    const int nt = blockIdx.x % 48;
    const int m0 = mt << 7, n0 = nt << 7;

    const int tid  = threadIdx.x;
    const int lane = tid & 63;
    const int wave = tid >> 6;
    const int l15  = lane & 15;
    const int quad = lane >> 4;
    const int wm = (wave >> 1) * 64;
    const int wn = (wave & 1) * 64;

    f32x4 acc[4][4];
#pragma unroll
    for (int i = 0; i < 4; i++)
#pragma unroll
        for (int j = 0; j < 4; j++) acc[i][j] = {0.f, 0.f, 0.f, 0.f};

    for (int k0 = 0; k0 < 1024; k0 += 64) {
#pragma unroll
        for (int it = 0; it < 4; it++) {
            int c  = it * 256 + tid;        // 16B chunk id 0..1023
            int r  = c >> 3;                // tile row
            int sl = (c & 7) ^ (r & 7);     // swizzled logical slot
            const unsigned short* ga = A  + (size_t)(m0 + r) * 1024 + k0 + sl * 8;
            const unsigned short* gb = Bt + (size_t)(n0 + r) * 1024 + k0 + sl * 8;
            __builtin_amdgcn_global_load_lds(
                (const __attribute__((address_space(1))) void*)ga,
                (__attribute__((address_space(3))) void*)&As[c * 8], 16, 0, 0);
            __builtin_amdgcn_global_load_lds(
                (const __attribute__((address_space(1))) void*)gb,
                (__attribute__((address_space(3))) void*)&Bs[c * 8], 16, 0, 0);
        }
        __syncthreads();

#pragma unroll
        for (int ks = 0; ks < 2; ks++) {
            short8 af[4], bf[4];
#pragma unroll
            for (int i = 0; i < 4; i++) {
                int row = wm + i * 16 + l15;
                int ph = (quad + ks * 4) ^ (row & 7);
                af[i] = *(const short8*)&As[row * 64 + ph * 8];
            }
#pragma unroll
            for (int j = 0; j < 4; j++) {
                int row = wn + j * 16 + l15;
                int ph = (quad + ks * 4) ^ (row & 7);
                bf[j] = *(const short8*)&Bs[row * 64 + ph * 8];
            }
#pragma unroll
            for (int i = 0; i < 4; i++)
#pragma unroll
                for (int j = 0; j < 4; j++)
                    acc[i][j] = __builtin_amdgcn_mfma_f32_16x16x32_bf16(af[i], bf[j], acc[i][j], 0, 0, 0);
        }
        __syncthreads();
    }

    if (nt < 16) {
        // S = silu(acc) -> bf16
#pragma unroll
        for (int i = 0; i < 4; i++)
#pragma unroll
            for (int j = 0; j < 4; j++) {
                int col = n0 + wn + j * 16 + l15;
#pragma unroll
                for (int r = 0; r < 4; r++) {
                    int row = m0 + wm + i * 16 + quad * 4 + r;
                    float v = acc[i][j][r];
                    v = v / (1.f + __expf(-v));
                    Sout[(size_t)row * 2048 + col] = f2bf(v);
                }
            }
    } else {
        // poly = h1*(1+h2); even fragment = h1, odd = h2, same poly column.
        // Also reduce per-chunk column sums (this block == one (b, ck, 64-col) cell).
        if (tid < 64) psum[tid] = 0.f;
        __syncthreads();
        int pbase = ((n0 - 2048 + wn) >> 1);
        float lsum0 = 0.f, lsum1 = 0.f;
#pragma unroll
        for (int i = 0; i < 4; i++) {
#pragma unroll
            for (int j = 0; j < 4; j += 2) {
                int pcol = pbase + (j >> 1) * 16 + l15;
#pragma unroll
                for (int r = 0; r < 4; r++) {
                    int row = m0 + wm + i * 16 + quad * 4 + r;
                    float pv = acc[i][j][r] * (1.f + acc[i][j + 1][r]);
                    Pout[(size_t)row * 2048 + pcol] = f2bf(pv);
                    if (j == 0) lsum0 += pv; else lsum1 += pv;
                }
            }
        }
        int pcl = (wn >> 1) + l15;   // block-local poly col for j=0
        atomicAdd(&psum[pcl], lsum0);
        atomicAdd(&psum[pcl + 16], lsum1);
        __syncthreads();
        if (tid < 64) {
            int b = m0 >> 12, ck = (m0 & 4095) >> 7;
            part[((size_t)b * NCK + ck) * 2048 + ((n0 - 2048) >> 1) + tid] = psum[tid];
        }
    }
}

// ---------------- final GEMM: out = M @ W_out  (16384x2048x1024, fp32 out) ----------------
__global__ __launch_bounds__(256) void gemm_out_kernel(
    const unsigned short* __restrict__ A,    // 16384 x 2048 bf16 (M)
    const unsigned short* __restrict__ Bt,   // 1024 x 2048 bf16
    float* __restrict__ Cout)
{
    __shared__ __align__(16) unsigned short As[128 * 64];
    __shared__ __align__(16) unsigned short Bs[128 * 64];

    const int mt = blockIdx.x >> 3;
    const int nt = blockIdx.x & 7;
    const int m0 = mt << 7, n0 = nt << 7;

    const int tid  = threadIdx.x;
    const int lane = tid & 63;
    const int wave = tid >> 6;
    const int l15  = lane & 15;
    const int quad = lane >> 4;
    const int wm = (wave >> 1) * 64;
    const int wn = (wave & 1) * 64;

    f32x4 acc[4][4];
#pragma unroll
    for (int i = 0; i < 4; i++)
#pragma unroll
        for (int j = 0; j < 4; j++) acc[i][j] = {0.f, 0.f, 0.f, 0.f};

    for (int k0 = 0; k0 < 2048; k0 += 64) {
#pragma unroll
        for (int it = 0; it < 4; it++) {
            int c  = it * 256 + tid;
            int r  = c >> 3;
            int sl = (c & 7) ^ (r & 7);
            const unsigned short* ga = A  + (size_t)(m0 + r) * 2048 + k0 + sl * 8;
            const unsigned short* gb = Bt + (size_t)(n0 + r) * 2048 + k0 + sl * 8;
            __builtin_amdgcn_global_load_lds(
                (const __attribute__((address_space(1))) void*)ga,
                (__attribute__((address_space(3))) void*)&As[c * 8], 16, 0, 0);
            __builtin_amdgcn_global_load_lds(
                (const __attribute__((address_space(1))) void*)gb,
                (__attribute__((address_space(3))) void*)&Bs[c * 8], 16, 0, 0);
        }
        __syncthreads();

#pragma unroll
        for (int ks = 0; ks < 2; ks++) {
            short8 af[4], bf[4];
#pragma unroll
            for (int i = 0; i < 4; i++) {
                int row = wm + i * 16 + l15;
                int ph = (quad + ks * 4) ^ (row & 7);
                af[i] = *(const short8*)&As[row * 64 + ph * 8];
            }
#pragma unroll
            for (int j = 0; j < 4; j++) {
                int row = wn + j * 16 + l15;
                int ph = (quad + ks * 4) ^ (row & 7);
                bf[j] = *(const short8*)&Bs[row * 64 + ph * 8];
            }
#pragma unroll
            for (int i = 0; i < 4; i++)
#pragma unroll
                for (int j = 0; j < 4; j++)
                    acc[i][j] = __builtin_amdgcn_mfma_f32_16x16x32_bf16(af[i], bf[j], acc[i][j], 0, 0, 0);
        }
        __syncthreads();
    }

#pragma unroll
    for (int i = 0; i < 4; i++)
#pragma unroll
        for (int j = 0; j < 4; j++) {
            int col = n0 + wn + j * 16 + l15;
#pragma unroll
            for (int r = 0; r < 4; r++) {
                int row = m0 + wm + i * 16 + quad * 4 + r;
                Cout[(size_t)row * 1024 + col] = acc[i][j][r];
            }
        }
}

// ---------------- scan phase 2: exclusive scan over chunks ----------------
__global__ void chunk_scan_kernel(float* __restrict__ part) {
    int idx = blockIdx.x * blockDim.x + threadIdx.x;   // 8192 columns
    int b = idx >> 11, col = idx & 2047;
    float run = 0.f;
    for (int ck = 0; ck < NCK; ck++) {
        size_t off = ((size_t)b * NCK + ck) * 2048 + col;
        float v = part[off];
        part[off] = run;
        run += v;
    }
}

// ---------------- scan phase 3: M = s * (cumsum/t), in place over poly ----------------
__global__ void finalize_kernel(unsigned short* __restrict__ poly, const unsigned short* __restrict__ s,
                                const float* __restrict__ part) {
    int seg = blockIdx.x & 3;
    int ck  = (blockIdx.x >> 2) & (NCK - 1);
    int b   = blockIdx.x >> 7;
    int cp  = seg * 256 + threadIdx.x;
    size_t po = ((size_t)b * NCK + ck) * 2048 + cp * 2;
    float run0 = part[po], run1 = part[po + 1];
    size_t base = ((size_t)b * TT + (size_t)ck * CKS) * 2048 + cp * 2;
    for (int t = 0; t < CKS; t++) {
        int tg = ck * CKS + t;
        size_t off = base + (size_t)t * 2048;
        uint32_t pv = *(const uint32_t*)&poly[off];
        run0 += bf_lo(pv);
        run1 += bf_hi(pv);
        float inv = 1.f / (float)(tg + 1);
        uint32_t sv = *(const uint32_t*)&s[off];
        float m0 = bf_lo(sv) * run0 * inv;
        float m1 = bf_hi(sv) * run1 * inv;
        *(uint32_t*)&poly[off] = pack2bf(m0, m1);
    }
}

extern "C" void kernel_launch(void* const* d_in, const int* in_sizes, int n_in,
                              void* d_out, int out_size, void* d_ws, size_t ws_size,
                              hipStream_t stream) {
    const float* x     = (const float*)d_in[0];
    const float* W_sel = (const float*)d_in[1];
    const float* W_agg = (const float*)d_in[2];
    const float* W_out = (const float*)d_in[3];
    const float* sqk_q = (const float*)d_in[4];
    const float* sqk_k = (const float*)d_in[5];
    float* out = (float*)d_out;

    char* ws = (char*)d_ws;
    unsigned short* xb    = (unsigned short*)(ws);                   // 32 MB
    unsigned short* wallT = (unsigned short*)(ws + 33554432ull);     // 6144x1024 bf16 (12 MB)
    unsigned short* woutT = (unsigned short*)(ws + 46137344ull);     // 1024x2048 bf16 (4 MB)
    unsigned short* s_b   = (unsigned short*)(ws + 50331648ull);     // 16384x2048 bf16 (64 MB)
    unsigned short* poly  = (unsigned short*)(ws + 117440512ull);    // 16384x2048 bf16 (64 MB)
    float*          part  = (float*)(ws + 184549376ull);             // 4x32x2048 fp32 (1 MB)

    dim3 tb(32, 8);
    conv_x_kernel<<<(MM * CC / 4 + 255) / 256, 256, 0, stream>>>(x, xb, MM * CC / 4);
    trans_direct_kernel<<<dim3(HH / 32, CC / 32), tb, 0, stream>>>(W_sel, wallT, sqk_q, CC, HH);
    trans_pair_kernel<<<dim3(4096 / 32, CC / 32), tb, 0, stream>>>(W_agg, wallT + 2048ull * 1024, sqk_k);
    trans_direct_kernel<<<dim3(CC / 32, HH / 32), tb, 0, stream>>>(W_out, woutT, nullptr, HH, CC);

    // fused: S (silu) + poly + chunk sums, one dispatch
    gemm_fused_kernel<<<(MM / 128) * 48, 256, 0, stream>>>(xb, wallT, s_b, poly, part);

    chunk_scan_kernel<<<(BB * HH) / 256, 256, 0, stream>>>(part);
    finalize_kernel<<<BB * NCK * 4, 256, 0, stream>>>(poly, s_b, part);

    // out = M @ W_out
    gemm_out_kernel<<<(MM / 128) * (CC / 128), 256, 0, stream>>>(poly, woutT, out);
}